// Round 7
// baseline (160.526 us; speedup 1.0000x reference)
//
#include <hip/hip_runtime.h>
#include <hip/hip_bf16.h>

#define N_NODES 8192
#define DIM 128
#define MASK_THRESH 0.8f
#define RB 128            // row-blocks: 8192 / 64 rows
#define KSTEP 64          // k elements staged per step

using f32x4  = __attribute__((ext_vector_type(4))) float;
using bf16x8 = __attribute__((ext_vector_type(8))) short;

static __device__ __forceinline__ short f2bf(float f) {
    unsigned u = __builtin_bit_cast(unsigned, f);
    u += 0x7fffu + ((u >> 16) & 1u);
    return (short)(u >> 16);
}

// async global->LDS, 16B/lane; LDS dest = wave-uniform base (+lane*16 implicit)
static __device__ __forceinline__ void gload16(const void* gsrc, void* ldst) {
    __builtin_amdgcn_global_load_lds(
        (const __attribute__((address_space(1))) unsigned int*)gsrc,
        (__attribute__((address_space(3))) unsigned int*)ldst,
        16, 0, 0);
}

// ---------------------------------------------------------------------------
// Kernel 1: V = X@W^T + b stored FRAGMENT-MAJOR as bf16:
//   Vf[((kb*8 + t)*64 + lane)*8 + e] = V[j][d],
//   j = kb*32 + (lane>>4)*8 + e, d = t*16 + (lane&15).   (verified R5/R6)
// ---------------------------------------------------------------------------
__global__ __launch_bounds__(256) void build_vf_kernel(
    const float* __restrict__ X, const float* __restrict__ W,
    const float* __restrict__ bias, short* __restrict__ Vf) {
    __shared__ float xs[32][128];
    const int jt = blockIdx.x * 32;
    for (int e = threadIdx.x; e < 32 * 128; e += 256) {
        xs[e >> 7][e & 127] = X[(size_t)(jt + (e >> 7)) * DIM + (e & 127)];
    }
    __syncthreads();
    const int d  = threadIdx.x & 127;
    const int jh = threadIdx.x >> 7;
    float bv = bias[d];
    float acc[16];
#pragma unroll
    for (int i = 0; i < 16; i++) acc[i] = bv;
    const float* wrow = W + (size_t)d * DIM;
    for (int k = 0; k < DIM; k += 4) {
        f32x4 wv = *(const f32x4*)(wrow + k);
#pragma unroll
        for (int i = 0; i < 16; i++) {
            f32x4 xv = *(const f32x4*)(&xs[jh * 16 + i][k]);
            acc[i] = fmaf(xv[0], wv[0], acc[i]);
            acc[i] = fmaf(xv[1], wv[1], acc[i]);
            acc[i] = fmaf(xv[2], wv[2], acc[i]);
            acc[i] = fmaf(xv[3], wv[3], acc[i]);
        }
    }
    bf16x8 o0, o1;
#pragma unroll
    for (int i = 0; i < 8; i++) { o0[i] = f2bf(acc[i]); o1[i] = f2bf(acc[8 + i]); }
    const int kb = jt >> 5;
    const int t  = d >> 4;
    short* base = Vf + ((size_t)(kb * 8 + t) * 64 + (d & 15) + 32 * jh) * 8;
    *(bf16x8*)(base)       = o0;
    *(bf16x8*)(base + 128) = o1;
}

// ---------------------------------------------------------------------------
// Kernel 2: fused masked-softmax(A) @ V, occupancy-tuned.
//   Block: 256 thr (4 waves), tile 64 rows x 128 cols; wave (wr,wc) owns
//   32x64 (acc[2][4] = 32 regs). KSTEP=64: A tile [64][64] f32, 2x16KB dbuf,
//   swizzled-source gload16 -> linear LDS -> swizzled ds_read_b128.
//   B-frags direct from L2-resident Vf (contiguous 1KB loads, reused x2 rg).
//   5 blocks/CU by LDS (zs overlaid in abuf); grid = RB*S, 4 resident/CU.
// ---------------------------------------------------------------------------
template <int WRITE_PARTIAL>
__global__ __launch_bounds__(256, 5) void fused_kernel(
    const float* __restrict__ A, const short* __restrict__ Vf,
    float* __restrict__ dst, float* __restrict__ Zp, int kchunk, int S) {

    __shared__ __align__(16) float abuf[8192];   // 2 x 16KB A tiles (+zs overlay)

    const int tid   = threadIdx.x;
    const int wid   = tid >> 6;
    const int lane  = tid & 63;
    const int row_a = lane & 15;
    const int kg    = lane >> 4;
    const int wr    = wid & 1;           // row half (32 rows)
    const int wc    = wid >> 1;          // col half (64 cols)
    const int rb    = blockIdx.x / S;
    const int chunk = blockIdx.x - rb * S;   // chunk fast -> chunk == XCD
    const int r0    = rb * 64;
    const int k0    = chunk * kchunk;
    const int nsteps = kchunk >> 6;

    f32x4 acc[2][4];
#pragma unroll
    for (int rg = 0; rg < 2; rg++)
#pragma unroll
        for (int t = 0; t < 4; t++) acc[rg][t] = (f32x4)0.0f;
    float zacc[2] = {0.0f, 0.0f};

    // staging: 4 gload16/wave, each 4 rows x 256B; source pre-swizzled
    const float* asrc[4]; int adst[4];
#pragma unroll
    for (int i = 0; i < 4; i++) {
        const int row_s = wid * 16 + i * 4 + (lane >> 4);
        asrc[i] = A + (size_t)(r0 + row_s) * N_NODES + k0
                    + (((lane & 15) ^ (row_s & 7)) << 2);
        adst[i] = (wid * 16 + i * 4) * 64;
    }

    // prologue: stage step 0 into buf half 0
#pragma unroll
    for (int i = 0; i < 4; i++) gload16(asrc[i], abuf + adst[i]);

    for (int ks = 0; ks < nsteps; ks++) {
        __syncthreads();                 // stage(ks) visible; buf[ks-1] reads done
        if (ks + 1 < nsteps) {
            float* nb = abuf + ((ks + 1) & 1) * 4096;
#pragma unroll
            for (int i = 0; i < 4; i++)
                gload16(asrc[i] + (size_t)(ks + 1) * KSTEP, nb + adst[i]);
        }
        const float* ab = abuf + (ks & 1) * 4096;
        const int kbg = (k0 >> 5) + ks * 2;
#pragma unroll
        for (int kb = 0; kb < 2; kb++) {
            bf16x8 bv[4];
#pragma unroll
            for (int t = 0; t < 4; t++)
                bv[t] = *(const bf16x8*)(Vf + ((size_t)(kbg + kb) * 8 + wc * 4 + t) * 512 + lane * 8);
#pragma unroll
            for (int rg = 0; rg < 2; rg++) {
                const int base = (wr * 32 + rg * 16 + row_a) * 64;
                const int c0   = kb * 8 + kg * 2;
                const f32x4 av0 = *(const f32x4*)(ab + base + (((c0 + 0) ^ (row_a & 7)) << 2));
                const f32x4 av1 = *(const f32x4*)(ab + base + (((c0 + 1) ^ (row_a & 7)) << 2));
                float p[8];
#pragma unroll
                for (int i = 0; i < 4; i++) {
                    p[i]     = (av0[i] > MASK_THRESH) ? __expf(av0[i]) : 0.0f;
                    p[i + 4] = (av1[i] > MASK_THRESH) ? __expf(av1[i]) : 0.0f;
                }
                bf16x8 af;
#pragma unroll
                for (int i = 0; i < 8; i++) { zacc[rg] += p[i]; af[i] = f2bf(p[i]); }
#pragma unroll
                for (int t = 0; t < 4; t++)
                    acc[rg][t] = __builtin_amdgcn_mfma_f32_16x16x32_bf16(af, bv[t], acc[rg][t], 0, 0, 0);
            }
        }
    }

    // fold kg groups: every lane ends with its row_a's total (within chunk)
#pragma unroll
    for (int rg = 0; rg < 2; rg++) {
        zacc[rg] += __shfl_xor(zacc[rg], 16);
        zacc[rg] += __shfl_xor(zacc[rg], 32);
    }

    if (WRITE_PARTIAL) {
        float* nd = dst + (size_t)chunk * N_NODES * DIM;
#pragma unroll
        for (int rg = 0; rg < 2; rg++)
#pragma unroll
            for (int t = 0; t < 4; t++)
#pragma unroll
                for (int r = 0; r < 4; r++) {
                    const int row = r0 + wr * 32 + rg * 16 + kg * 4 + r;
                    const int col = wc * 64 + t * 16 + row_a;
                    nd[(size_t)row * DIM + col] = acc[rg][t][r];
                }
        if (wc == 0 && lane < 16) {
#pragma unroll
            for (int rg = 0; rg < 2; rg++)
                Zp[(size_t)chunk * N_NODES + r0 + wr * 32 + rg * 16 + lane] = zacc[rg];
        }
    } else {
        __syncthreads();                 // all tile reads done; overlay zs
        float* zsm = abuf;               // [64]
        if (wc == 0 && lane < 16) {
            zsm[wr * 32 + lane]      = zacc[0];
            zsm[wr * 32 + 16 + lane] = zacc[1];
        }
        __syncthreads();
#pragma unroll
        for (int rg = 0; rg < 2; rg++)
#pragma unroll
            for (int t = 0; t < 4; t++)
#pragma unroll
                for (int r = 0; r < 4; r++) {
                    const int rl  = wr * 32 + rg * 16 + kg * 4 + r;
                    const int col = wc * 64 + t * 16 + row_a;
                    const float v = acc[rg][t][r] / zsm[rl];
                    dst[(size_t)(r0 + rl) * DIM + col] = (v > 0.0f) ? v : 0.01f * v;
                }
    }
}

// ---------------------------------------------------------------------------
// Kernel 3: sum S partials, normalize, leaky_relu. float4 per thread.
// ---------------------------------------------------------------------------
__global__ __launch_bounds__(256) void reduce_kernel(
    const float* __restrict__ num, const float* __restrict__ Zp,
    float* __restrict__ out, int S) {
    const size_t i4 = (size_t)blockIdx.x * 256 + threadIdx.x;  // quad index
    const int r  = (int)(i4 >> 5);
    const int c4 = (int)(i4 & 31) * 4;
    f32x4 s = (f32x4)0.0f;
    float z = 0.0f;
    for (int p = 0; p < S; p++) {
        s += *(const f32x4*)(num + ((size_t)p * N_NODES + r) * DIM + c4);
        z += Zp[(size_t)p * N_NODES + r];
    }
    f32x4 o;
#pragma unroll
    for (int j = 0; j < 4; j++) {
        const float v = s[j] / z;
        o[j] = (v > 0.0f) ? v : 0.01f * v;
    }
    *(f32x4*)(out + (size_t)r * DIM + c4) = o;
}

extern "C" void kernel_launch(void* const* d_in, const int* in_sizes, int n_in,
                              void* d_out, int out_size, void* d_ws, size_t ws_size,
                              hipStream_t stream) {
    const float* A = (const float*)d_in[0];
    const float* X = (const float*)d_in[1];
    const float* W = (const float*)d_in[2];
    const float* b = (const float*)d_in[3];
    float* out = (float*)d_out;

    const size_t VF_BYTES = (size_t)DIM * N_NODES * 2;   // 2 MiB
    short* Vf = (short*)d_ws;
    build_vf_kernel<<<N_NODES / 32, 256, 0, stream>>>(X, W, b, Vf);

    const size_t per_split = ((size_t)N_NODES * DIM + N_NODES) * sizeof(float);
    int S = 1;
    for (int cand = 8; cand >= 1; cand >>= 1) {
        if (VF_BYTES + (size_t)cand * per_split <= ws_size) { S = cand; break; }
    }

    if (S >= 2) {
        float* num = (float*)((char*)d_ws + VF_BYTES);
        float* Zp  = num + (size_t)S * N_NODES * DIM;
        fused_kernel<1><<<RB * S, 256, 0, stream>>>(A, Vf, num, Zp, N_NODES / S, S);
        reduce_kernel<<<(N_NODES * DIM / 4) / 256, 256, 0, stream>>>(num, Zp, out, S);
    } else {
        fused_kernel<0><<<RB, 256, 0, stream>>>(A, Vf, out, nullptr, N_NODES, 1);
    }
}

// Round 8
// 109.318 us; speedup vs baseline: 1.4684x; 1.4684x over previous
//
#include <hip/hip_runtime.h>
#include <hip/hip_bf16.h>

#define N_NODES 8192
#define DIM 128
#define MASK_THRESH 0.8f
#define ROWS 64
#define RB (N_NODES / ROWS)   // 128 row-blocks
#define KSTEP 64              // k elements per pipeline step

using f32x4  = __attribute__((ext_vector_type(4))) float;
using bf16x8 = __attribute__((ext_vector_type(8))) short;

static __device__ __forceinline__ short f2bf(float f) {
    unsigned u = __builtin_bit_cast(unsigned, f);
    u += 0x7fffu + ((u >> 16) & 1u);
    return (short)(u >> 16);
}

// async global->LDS, 16B/lane; LDS dest = wave-uniform base (+lane*16 implicit)
static __device__ __forceinline__ void gload16(const void* gsrc, void* ldst) {
    __builtin_amdgcn_global_load_lds(
        (const __attribute__((address_space(1))) unsigned int*)gsrc,
        (__attribute__((address_space(3))) unsigned int*)ldst,
        16, 0, 0);
}

// ---------------------------------------------------------------------------
// Kernel 1: V = X@W^T + b stored FRAGMENT-MAJOR as bf16:
//   Vf[((kb*8 + t)*64 + lane)*8 + e] = V[j][d],
//   j = kb*32 + (lane>>4)*8 + e, d = t*16 + (lane&15).   (verified R5-R7)
// ---------------------------------------------------------------------------
__global__ __launch_bounds__(256) void build_vf_kernel(
    const float* __restrict__ X, const float* __restrict__ W,
    const float* __restrict__ bias, short* __restrict__ Vf) {
    __shared__ float xs[32][128];
    const int jt = blockIdx.x * 32;
    for (int e = threadIdx.x; e < 32 * 128; e += 256) {
        xs[e >> 7][e & 127] = X[(size_t)(jt + (e >> 7)) * DIM + (e & 127)];
    }
    __syncthreads();
    const int d  = threadIdx.x & 127;
    const int jh = threadIdx.x >> 7;
    float bv = bias[d];
    float acc[16];
#pragma unroll
    for (int i = 0; i < 16; i++) acc[i] = bv;
    const float* wrow = W + (size_t)d * DIM;
    for (int k = 0; k < DIM; k += 4) {
        f32x4 wv = *(const f32x4*)(wrow + k);
#pragma unroll
        for (int i = 0; i < 16; i++) {
            f32x4 xv = *(const f32x4*)(&xs[jh * 16 + i][k]);
            acc[i] = fmaf(xv[0], wv[0], acc[i]);
            acc[i] = fmaf(xv[1], wv[1], acc[i]);
            acc[i] = fmaf(xv[2], wv[2], acc[i]);
            acc[i] = fmaf(xv[3], wv[3], acc[i]);
        }
    }
    bf16x8 o0, o1;
#pragma unroll
    for (int i = 0; i < 8; i++) { o0[i] = f2bf(acc[i]); o1[i] = f2bf(acc[8 + i]); }
    const int kb = jt >> 5;
    const int t  = d >> 4;
    short* base = Vf + ((size_t)(kb * 8 + t) * 64 + (d & 15) + 32 * jh) * 8;
    *(bf16x8*)(base)       = o0;
    *(bf16x8*)(base + 128) = o1;
}

// ---------------------------------------------------------------------------
// Kernel 2: fused masked-softmax(A) @ V — counted-vmcnt pipeline (T3/T4).
//   Block: 512 thr (8 waves) = 64 rows x 128 cols; wave (wr,wc) owns 32x32.
//   Per KSTEP=64 step: stage A[64][64] f32 (16KB, ^row&15 swizzled source ->
//   linear LDS -> swizzled ds_read) + Vf frag-slab (16KB contiguous) via
//   global_load_lds. Compute phase has ZERO VMEM. Loop:
//     [s_waitcnt vmcnt(4); s_barrier]  compute(ks)  [s_barrier]  stage(ks+2)
//   -> stage(ks+1) stays in flight across compute(ks); never vmcnt(0) in loop.
// ---------------------------------------------------------------------------
template <int WRITE_PARTIAL>
__global__ __launch_bounds__(512, 4) void fused_kernel(
    const float* __restrict__ A, const short* __restrict__ Vf,
    float* __restrict__ dst, float* __restrict__ Zp, int kchunk, int S) {

    __shared__ __align__(16) float abuf[2 * 64 * 64];   // 32 KB
    __shared__ __align__(16) short vbuf[2 * 16 * 512];  // 32 KB
    __shared__ float zs[64];

    const int tid   = threadIdx.x;
    const int wid   = tid >> 6;
    const int lane  = tid & 63;
    const int row_a = lane & 15;
    const int kg    = lane >> 4;
    const int wr    = wid >> 2;          // row half (32 rows)
    const int wc    = wid & 3;           // col quad (32 cols)
    const int rb    = blockIdx.x / S;
    const int chunk = blockIdx.x - rb * S;
    const int r0    = rb * ROWS;
    const int k0    = chunk * kchunk;
    const int nsteps = kchunk >> 6;

    // --- A staging: 2 gloads/wave, 4 rows x 256B each, source pre-swizzled ---
    const float* asrcA[2]; int adstA[2];
#pragma unroll
    for (int i = 0; i < 2; i++) {
        const int rowt = wid * 8 + i * 4 + (lane >> 4);
        asrcA[i] = A + (size_t)(r0 + rowt) * N_NODES + k0
                     + (((lane & 15) ^ (rowt & 15)) << 2);
        adstA[i] = (wid * 8 + i * 4) * 64;           // wave-uniform dest base
    }
    // --- V staging: 2 gloads/wave, contiguous 1KB frags (fragment-major) ---
    const short* vsrcV = Vf + ((size_t)(k0 >> 5) * 8 + wid * 2) * 512 + lane * 8;
    const int vdst0 = wid * 2 * 512;                 // shorts, wave-uniform

    f32x4 acc[2][2];
#pragma unroll
    for (int rg = 0; rg < 2; rg++)
#pragma unroll
        for (int t = 0; t < 2; t++) acc[rg][t] = (f32x4)0.0f;
    float zacc[2] = {0.0f, 0.0f};

    auto stage = [&](int s, int b) {
#pragma unroll
        for (int i = 0; i < 2; i++)
            gload16(asrcA[i] + (size_t)s * KSTEP, abuf + b * 4096 + adstA[i]);
#pragma unroll
        for (int j = 0; j < 2; j++)
            gload16(vsrcV + (size_t)s * 8192 + j * 512, vbuf + b * 8192 + vdst0 + j * 512);
    };

    // prologue: two batches in flight
    stage(0, 0);
    stage(1, 1);

    for (int ks = 0; ks < nsteps; ks++) {
        // wait stage(ks) done (stage(ks+1)'s 4 loads stay outstanding), publish
        asm volatile("s_waitcnt vmcnt(4)\n\ts_barrier" ::: "memory");

        const float* ab = abuf + (ks & 1) * 4096;
        const short* vb = vbuf + (ks & 1) * 8192;
#pragma unroll
        for (int kb = 0; kb < 2; kb++) {
            const bf16x8 bv0 = *(const bf16x8*)(vb + (kb * 8 + wc * 2 + 0) * 512 + lane * 8);
            const bf16x8 bv1 = *(const bf16x8*)(vb + (kb * 8 + wc * 2 + 1) * 512 + lane * 8);
#pragma unroll
            for (int rg = 0; rg < 2; rg++) {
                const int rbase = (wr * 32 + rg * 16 + row_a) * 64;
                const int c0    = kb * 8 + kg * 2;
                const f32x4 av0 = *(const f32x4*)(ab + rbase + (((c0 + 0) ^ row_a) << 2));
                const f32x4 av1 = *(const f32x4*)(ab + rbase + (((c0 + 1) ^ row_a) << 2));
                float p[8];
#pragma unroll
                for (int i = 0; i < 4; i++) {
                    p[i]     = (av0[i] > MASK_THRESH) ? __expf(av0[i]) : 0.0f;
                    p[i + 4] = (av1[i] > MASK_THRESH) ? __expf(av1[i]) : 0.0f;
                }
                bf16x8 af;
#pragma unroll
                for (int i = 0; i < 8; i++) { zacc[rg] += p[i]; af[i] = f2bf(p[i]); }
                acc[rg][0] = __builtin_amdgcn_mfma_f32_16x16x32_bf16(af, bv0, acc[rg][0], 0, 0, 0);
                acc[rg][1] = __builtin_amdgcn_mfma_f32_16x16x32_bf16(af, bv1, acc[rg][1], 0, 0, 0);
            }
        }

        // all waves done reading buf[ks&1]; safe to re-stage it
        asm volatile("s_barrier" ::: "memory");
        const int stg = (ks + 2 < nsteps) ? (ks + 2) : (nsteps - 1);  // uniform issue
        stage(stg, ks & 1);
    }

    asm volatile("s_waitcnt vmcnt(0)" ::: "memory");
    __syncthreads();

    // --- Z: fold 4 kg groups; every lane holds its row_a's chunk-sum ---
#pragma unroll
    for (int rg = 0; rg < 2; rg++) {
        zacc[rg] += __shfl_xor(zacc[rg], 16);
        zacc[rg] += __shfl_xor(zacc[rg], 32);
    }

    if (WRITE_PARTIAL) {
        float* nd = dst + (size_t)chunk * N_NODES * DIM;
#pragma unroll
        for (int rg = 0; rg < 2; rg++)
#pragma unroll
            for (int t = 0; t < 2; t++)
#pragma unroll
                for (int r = 0; r < 4; r++) {
                    const int row = r0 + wr * 32 + rg * 16 + kg * 4 + r;
                    const int col = wc * 32 + t * 16 + row_a;
                    nd[(size_t)row * DIM + col] = acc[rg][t][r];
                }
        if (wc == 0 && lane < 16) {
#pragma unroll
            for (int rg = 0; rg < 2; rg++)
                Zp[(size_t)chunk * N_NODES + r0 + wr * 32 + rg * 16 + lane] = zacc[rg];
        }
    } else {
        if (wc == 0 && lane < 16) {
#pragma unroll
            for (int rg = 0; rg < 2; rg++) zs[wr * 32 + rg * 16 + lane] = zacc[rg];
        }
        __syncthreads();
#pragma unroll
        for (int rg = 0; rg < 2; rg++)
#pragma unroll
            for (int t = 0; t < 2; t++)
#pragma unroll
                for (int r = 0; r < 4; r++) {
                    const int rl  = wr * 32 + rg * 16 + kg * 4 + r;
                    const int col = wc * 32 + t * 16 + row_a;
                    const float v = acc[rg][t][r] / zs[rl];
                    dst[(size_t)(r0 + rl) * DIM + col] = (v > 0.0f) ? v : 0.01f * v;
                }
    }
}

// ---------------------------------------------------------------------------
// Kernel 3: sum S partials, normalize, leaky_relu. float4 per thread.
// ---------------------------------------------------------------------------
__global__ __launch_bounds__(256) void reduce_kernel(
    const float* __restrict__ num, const float* __restrict__ Zp,
    float* __restrict__ out, int S) {
    const size_t i4 = (size_t)blockIdx.x * 256 + threadIdx.x;  // quad index
    const int r  = (int)(i4 >> 5);
    const int c4 = (int)(i4 & 31) * 4;
    f32x4 s = (f32x4)0.0f;
    float z = 0.0f;
    for (int p = 0; p < S; p++) {
        s += *(const f32x4*)(num + ((size_t)p * N_NODES + r) * DIM + c4);
        z += Zp[(size_t)p * N_NODES + r];
    }
    f32x4 o;
#pragma unroll
    for (int j = 0; j < 4; j++) {
        const float v = s[j] / z;
        o[j] = (v > 0.0f) ? v : 0.01f * v;
    }
    *(f32x4*)(out + (size_t)r * DIM + c4) = o;
}

extern "C" void kernel_launch(void* const* d_in, const int* in_sizes, int n_in,
                              void* d_out, int out_size, void* d_ws, size_t ws_size,
                              hipStream_t stream) {
    const float* A = (const float*)d_in[0];
    const float* X = (const float*)d_in[1];
    const float* W = (const float*)d_in[2];
    const float* b = (const float*)d_in[3];
    float* out = (float*)d_out;

    const size_t VF_BYTES = (size_t)DIM * N_NODES * 2;   // 2 MiB
    short* Vf = (short*)d_ws;
    build_vf_kernel<<<N_NODES / 32, 256, 0, stream>>>(X, W, b, Vf);

    const size_t per_split = ((size_t)N_NODES * DIM + N_NODES) * sizeof(float);
    int S = 1;
    for (int cand = 4; cand >= 1; cand >>= 1) {
        if (VF_BYTES + (size_t)cand * per_split <= ws_size) { S = cand; break; }
    }

    if (S >= 2) {
        float* num = (float*)((char*)d_ws + VF_BYTES);
        float* Zp  = num + (size_t)S * N_NODES * DIM;
        fused_kernel<1><<<RB * S, 512, 0, stream>>>(A, Vf, num, Zp, N_NODES / S, S);
        reduce_kernel<<<(N_NODES * DIM / 4) / 256, 256, 0, stream>>>(num, Zp, out, S);
    } else {
        fused_kernel<0><<<RB, 512, 0, stream>>>(A, Vf, out, nullptr, N_NODES, 1);
    }
}